// Round 20
// baseline (138.652 us; speedup 1.0000x reference)
//
#include <hip/hip_runtime.h>
#include <hip/hip_bf16.h>
#include <math.h>

constexpr int N = 16384, D = 256, C = 10000;
constexpr float S = 30.0f, MARGIN = 0.4f;
constexpr int BM = 256, BN = 80;             // C == 125*80 exactly: no padding
constexpr int NX = N / BM;                   // 64 row tiles
constexpr int NY = C / BN;                   // 125 col tiles
constexpr int NWG = NX * NY;                 // 8000 = 8 * 8 * 125
constexpr float S_LOG2E = 43.2808512266689f; // S * log2(e)

constexpr int PREPX_BLOCKS = N / 16;          // 1024 (16-row groups, frag pack)
constexpr int PREPW_BLOCKS = (C * D) / 1024;  // 2500 (plain bf16 rows)

using bf16 = __hip_bfloat16;
typedef __attribute__((ext_vector_type(8))) short short8;
typedef __attribute__((ext_vector_type(4))) short short4v;
typedef __attribute__((ext_vector_type(4))) float f32x4;

#define DRAIN_DMA()                                        \
    do {                                                   \
        asm volatile("s_waitcnt vmcnt(0)" ::: "memory");   \
        __builtin_amdgcn_sched_barrier(0);                 \
    } while (0)

__device__ inline short8 pack8(f32x4 a, f32x4 b, float sc) {
    short8 s;
    s[0] = (short)__bfloat16_as_ushort(__float2bfloat16(a.x * sc));
    s[1] = (short)__bfloat16_as_ushort(__float2bfloat16(a.y * sc));
    s[2] = (short)__bfloat16_as_ushort(__float2bfloat16(a.z * sc));
    s[3] = (short)__bfloat16_as_ushort(__float2bfloat16(a.w * sc));
    s[4] = (short)__bfloat16_as_ushort(__float2bfloat16(b.x * sc));
    s[5] = (short)__bfloat16_as_ushort(__float2bfloat16(b.y * sc));
    s[6] = (short)__bfloat16_as_ushort(__float2bfloat16(b.z * sc));
    s[7] = (short)__bfloat16_as_ushort(__float2bfloat16(b.w * sc));
    return s;
}

// ---------------- fused prep ----------------
// x: normalize + pre-scale by S*log2e, packed into 16x16x32 A-fragment order
//    (R9-verified). tgt in f32.
// W: plain row-major bf16 (no padding: C is a multiple of BN=80) — staged
//    into LDS by the GEMM via global_load_lds.
__global__ __launch_bounds__(256) void prep(const float* __restrict__ x,
                                            const int* __restrict__ labels,
                                            const float* __restrict__ W,
                                            bf16* __restrict__ Af,
                                            float* __restrict__ tgt,
                                            bf16* __restrict__ Wb,
                                            float* __restrict__ out) {
    const int bid = blockIdx.x;
    if (bid == 0 && threadIdx.x == 0) out[0] = 0.0f;

    if (bid < PREPX_BLOCKS) {
        const int tl = threadIdx.x;
        const int r = tl >> 4, c = tl & 15;
        const int rg = bid;
        const int row = rg * 16 + r;
        const float* xr = x + (size_t)row * D + c * 16;
        f32x4 v0 = *(const f32x4*)(xr + 0);
        f32x4 v1 = *(const f32x4*)(xr + 4);
        f32x4 v2 = *(const f32x4*)(xr + 8);
        f32x4 v3 = *(const f32x4*)(xr + 12);

        float ssq = v0.x*v0.x + v0.y*v0.y + v0.z*v0.z + v0.w*v0.w
                  + v1.x*v1.x + v1.y*v1.y + v1.z*v1.z + v1.w*v1.w
                  + v2.x*v2.x + v2.y*v2.y + v2.z*v2.z + v2.w*v2.w
                  + v3.x*v3.x + v3.y*v3.y + v3.z*v3.z + v3.w*v3.w;
        ssq += __shfl_xor(ssq, 1);
        ssq += __shfl_xor(ssq, 2);
        ssq += __shfl_xor(ssq, 4);
        ssq += __shfl_xor(ssq, 8);
        float rinv = rsqrtf(ssq);

        const int lab = labels[row];
        const float* wr = W + (size_t)lab * D + c * 16;
        f32x4 w0 = *(const f32x4*)(wr + 0);
        f32x4 w1 = *(const f32x4*)(wr + 4);
        f32x4 w2 = *(const f32x4*)(wr + 8);
        f32x4 w3 = *(const f32x4*)(wr + 12);
        float td = v0.x*w0.x + v0.y*w0.y + v0.z*w0.z + v0.w*w0.w
                 + v1.x*w1.x + v1.y*w1.y + v1.z*w1.z + v1.w*w1.w
                 + v2.x*w2.x + v2.y*w2.y + v2.z*w2.z + v2.w*w2.w
                 + v3.x*w3.x + v3.y*w3.y + v3.z*w3.z + v3.w*w3.w;
        td += __shfl_xor(td, 1);
        td += __shfl_xor(td, 2);
        td += __shfl_xor(td, 4);
        td += __shfl_xor(td, 8);
        if (c == 0) tgt[row] = td * rinv;

        const float sc = rinv * S_LOG2E;
        const size_t fb = ((size_t)rg * 8 + (c >> 1)) * 512;   // frag (rg, kk=c>>1)
        const int kq0 = (c & 1) * 2;
        *(short8*)(Af + fb + (size_t)(kq0 * 16 + r) * 8)       = pack8(v0, v1, sc);
        *(short8*)(Af + fb + (size_t)((kq0 + 1) * 16 + r) * 8) = pack8(v2, v3, sc);
    } else {
        // plain row-major W -> bf16 (C*D exactly, no padding)
        int i = ((bid - PREPX_BLOCKS) * 256 + threadIdx.x) * 4;
        f32x4 v = *(const f32x4*)(W + i);
        short4v sv;
        sv.x = (short)__bfloat16_as_ushort(__float2bfloat16(v.x));
        sv.y = (short)__bfloat16_as_ushort(__float2bfloat16(v.y));
        sv.z = (short)__bfloat16_as_ushort(__float2bfloat16(v.z));
        sv.w = (short)__bfloat16_as_ushort(__float2bfloat16(v.w));
        *(short4v*)(Wb + i) = sv;
    }
}

// ---------------- main GEMM + exp2 + per-tile row partials ----------------
// R13 structure with BN=80 (C = 125*80, zero padding): B panel [80][256]
// staged ONCE into 40 KB LDS (same XOR-swizzle) -> 4 blocks/CU (160 KB
// exactly), 16 waves/CU = 2x R13's occupancy. A frag-direct from L2, 1-deep
// ping-pong; barrier-free K-loop. Per-wave tile 64x80 (acc[4][5] = 80 VGPR,
// well under the 128 quantum). No epilogue column mask (no padded cols).
__global__ __launch_bounds__(256) void gemm_exp(const bf16* __restrict__ Af,
                                                const bf16* __restrict__ Wb,
                                                bf16* __restrict__ partial) { // [NY][N] bf16
    __shared__ __align__(16) bf16 Bs[BN * D];   // 40 KB: [col][k], granule-swizzled

    // ---- XCD-aware decode (bijective: NWG = 8 * 8 * 125) ----
    const int bid = blockIdx.x;
    const int xcd = bid & 7;
    const int idx = bid >> 3;          // 0..999
    const int xl  = idx & 7;           // x within XCD chunk (fast)
    const int y   = idx >> 3;          // 0..124 (slow)
    const int tile_r = (xcd * 8 + xl) * BM;
    const int tile_c = y * BN;

    const int t = threadIdx.x;
    const int lane = t & 63, w = t >> 6;   // wave w owns rows w*64..+64, all 80 cols

    // ---- prologue: stage B panel (40 chunks of 1KB = 2 rows x 512B) ----
    #pragma unroll
    for (int q = 0; q < 10; ++q) {
        int c = w * 10 + q;                       // chunk 0..39, wave-uniform
        int row = 2 * c + (lane >> 5);            // B-panel row (= class col) 0..79
        int srcg = (lane & 31) ^ (row & 7);       // pre-swizzled source granule
        const bf16* gb = Wb + (size_t)(tile_c + row) * D + srcg * 8;
        __builtin_amdgcn_global_load_lds(
            (const __attribute__((address_space(1))) void*)gb,
            (__attribute__((address_space(3))) void*)(Bs + c * 512),
            16, 0, 0);
    }
    DRAIN_DMA();
    __syncthreads();   // B panel fully visible; the ONLY K-path barrier

    // ---- A fragment pointers (frag-order buffer, contiguous 1KB per frag) ----
    const bf16* ap[4];
    #pragma unroll
    for (int m = 0; m < 4; ++m)
        ap[m] = Af + ((size_t)((tile_r >> 4) + w * 4 + m) * 8) * 512 + lane * 8;

    f32x4 acc[4][5] = {};
    short8 a[2][4];
    #pragma unroll
    for (int m = 0; m < 4; ++m) a[0][m] = *(const short8*)(ap[m]);

    const int g0 = lane >> 4;       // k-quad within fragment
    const int x7 = lane & 7;        // swizzle key (row&7 == lane&7 for frag rows)

    #pragma unroll
    for (int kk = 0; kk < 8; ++kk) {           // fully unrolled -> static indices
        const int cur = kk & 1, nxt = cur ^ 1;
        if (kk < 7) {
            #pragma unroll
            for (int m = 0; m < 4; ++m)
                a[nxt][m] = *(const short8*)(ap[m] + (kk + 1) * 512);
        }
        short8 bf[5];
        #pragma unroll
        for (int n = 0; n < 5; ++n) {
            int row = n * 16 + (lane & 15);                 // B-panel row (class col)
            int g = (kk * 4 + g0) ^ x7;                     // swizzled k-granule
            bf[n] = *(const short8*)(Bs + row * 256 + g * 8);
        }
        #pragma unroll
        for (int m = 0; m < 4; ++m)
            #pragma unroll
            for (int n = 0; n < 5; ++n)
                acc[m][n] = __builtin_amdgcn_mfma_f32_16x16x32_bf16(a[cur][m], bf[n], acc[m][n], 0, 0, 0);
    }

    __syncthreads();   // K-loop reads of Bs done; reuse as epilogue scratch
    float* eps = (float*)Bs;   // 256 floats

    // ---- epilogue: exp2(acc), row sums (rows unique per wave; all cols valid) ----
    #pragma unroll
    for (int m = 0; m < 4; ++m) {
        float rs[4] = {0.f, 0.f, 0.f, 0.f};
        #pragma unroll
        for (int n = 0; n < 5; ++n) {
            #pragma unroll
            for (int r = 0; r < 4; ++r)
                rs[r] += __builtin_amdgcn_exp2f(acc[m][n][r]);
        }
        #pragma unroll
        for (int r = 0; r < 4; ++r) {
            float v = rs[r];
            v += __shfl_xor(v, 1);
            v += __shfl_xor(v, 2);
            v += __shfl_xor(v, 4);
            v += __shfl_xor(v, 8);
            if ((lane & 15) == 0)
                eps[w * 64 + m * 16 + (lane >> 4) * 4 + r] = v;
        }
    }
    __syncthreads();
    partial[(size_t)y * N + tile_r + t] = __float2bfloat16(eps[t]);  // coalesced
}

// ---------------- loss: reduce partials + per-row loss + single atomic per block ----------------
__global__ __launch_bounds__(256) void loss_part(const float* __restrict__ tgt,
                                                 const bf16* __restrict__ partial,
                                                 float* __restrict__ out) {
    int i = blockIdx.x * 256 + threadIdx.x;   // row
    float sum = 0.0f;
    #pragma unroll 1
    for (int y = 0; y < NY; ++y)
        sum += __bfloat162float(partial[(size_t)y * N + i]);  // coalesced per y

    float tg = tgt[i];
    float num = S * (tg - MARGIN);
    float den = __expf(num) + sum - __expf(S * tg);
    float L = num - logf(den);

    float v = L;
    #pragma unroll
    for (int off = 1; off < 64; off <<= 1) v += __shfl_xor(v, off);
    __shared__ float s4[4];
    int lane = threadIdx.x & 63, w = threadIdx.x >> 6;
    if (lane == 0) s4[w] = v;
    __syncthreads();
    if (threadIdx.x == 0) {
        float bsum = s4[0] + s4[1] + s4[2] + s4[3];
        atomicAdd(out, -bsum / (float)N);
    }
}

// ---------------- launch ----------------
extern "C" void kernel_launch(void* const* d_in, const int* in_sizes, int n_in,
                              void* d_out, int out_size, void* d_ws, size_t ws_size,
                              hipStream_t stream) {
    const float* x = (const float*)d_in[0];
    const int* labels = (const int*)d_in[1];
    const float* W = (const float*)d_in[2];

    char* ws = (char*)d_ws;
    bf16* Af       = (bf16*)(ws);                    // N*D*2 (frag order)   =  8,388,608
    bf16* Wb       = (bf16*)(ws + 8388608);          // C*D*2 (row-major)    =  5,120,000
    float* tgt     = (float*)(ws + 13508608);        // N*4                  =     65,536
    bf16* partial  = (bf16*)(ws + 13574144);         // NY*N*2               =  4,096,000
    float* out = (float*)d_out;                      // total 17,670,144 < proven 18.8 MB

    prep<<<PREPX_BLOCKS + PREPW_BLOCKS, 256, 0, stream>>>(x, labels, W, Af, tgt, Wb, out);
    gemm_exp<<<NWG, 256, 0, stream>>>(Af, Wb, partial);
    loss_part<<<N / 256, 256, 0, stream>>>(tgt, partial, out);
}

// Round 21
// 116.295 us; speedup vs baseline: 1.1922x; 1.1922x over previous
//
#include <hip/hip_runtime.h>
#include <hip/hip_bf16.h>
#include <math.h>

constexpr int N = 16384, D = 256, C = 10000;
constexpr float S = 30.0f, MARGIN = 0.4f;
constexpr int BM = 256, BN = 80;             // C == 125*80 exactly: no padding
constexpr int NX = N / BM;                   // 64 row tiles
constexpr int NY = C / BN;                   // 125 col tiles
constexpr int NWG = NX * NY;                 // 8000 = 8 * 8 * 125
constexpr float S_LOG2E = 43.2808512266689f; // S * log2(e)

constexpr int PREPX_BLOCKS = N / 16;          // 1024 (16-row groups, frag pack)
constexpr int PREPW_BLOCKS = (C * D) / 1024;  // 2500 (plain bf16 rows)

using bf16 = __hip_bfloat16;
typedef __attribute__((ext_vector_type(8))) short short8;
typedef __attribute__((ext_vector_type(4))) short short4v;
typedef __attribute__((ext_vector_type(4))) float f32x4;

#define DRAIN_DMA()                                        \
    do {                                                   \
        asm volatile("s_waitcnt vmcnt(0)" ::: "memory");   \
        __builtin_amdgcn_sched_barrier(0);                 \
    } while (0)

__device__ inline short8 pack8(f32x4 a, f32x4 b, float sc) {
    short8 s;
    s[0] = (short)__bfloat16_as_ushort(__float2bfloat16(a.x * sc));
    s[1] = (short)__bfloat16_as_ushort(__float2bfloat16(a.y * sc));
    s[2] = (short)__bfloat16_as_ushort(__float2bfloat16(a.z * sc));
    s[3] = (short)__bfloat16_as_ushort(__float2bfloat16(a.w * sc));
    s[4] = (short)__bfloat16_as_ushort(__float2bfloat16(b.x * sc));
    s[5] = (short)__bfloat16_as_ushort(__float2bfloat16(b.y * sc));
    s[6] = (short)__bfloat16_as_ushort(__float2bfloat16(b.z * sc));
    s[7] = (short)__bfloat16_as_ushort(__float2bfloat16(b.w * sc));
    return s;
}

// ---------------- fused prep ----------------
__global__ __launch_bounds__(256) void prep(const float* __restrict__ x,
                                            const int* __restrict__ labels,
                                            const float* __restrict__ W,
                                            bf16* __restrict__ Af,
                                            float* __restrict__ tgt,
                                            bf16* __restrict__ Wb,
                                            float* __restrict__ out) {
    const int bid = blockIdx.x;
    if (bid == 0 && threadIdx.x == 0) out[0] = 0.0f;

    if (bid < PREPX_BLOCKS) {
        const int tl = threadIdx.x;
        const int r = tl >> 4, c = tl & 15;
        const int rg = bid;
        const int row = rg * 16 + r;
        const float* xr = x + (size_t)row * D + c * 16;
        f32x4 v0 = *(const f32x4*)(xr + 0);
        f32x4 v1 = *(const f32x4*)(xr + 4);
        f32x4 v2 = *(const f32x4*)(xr + 8);
        f32x4 v3 = *(const f32x4*)(xr + 12);

        float ssq = v0.x*v0.x + v0.y*v0.y + v0.z*v0.z + v0.w*v0.w
                  + v1.x*v1.x + v1.y*v1.y + v1.z*v1.z + v1.w*v1.w
                  + v2.x*v2.x + v2.y*v2.y + v2.z*v2.z + v2.w*v2.w
                  + v3.x*v3.x + v3.y*v3.y + v3.z*v3.z + v3.w*v3.w;
        ssq += __shfl_xor(ssq, 1);
        ssq += __shfl_xor(ssq, 2);
        ssq += __shfl_xor(ssq, 4);
        ssq += __shfl_xor(ssq, 8);
        float rinv = rsqrtf(ssq);

        const int lab = labels[row];
        const float* wr = W + (size_t)lab * D + c * 16;
        f32x4 w0 = *(const f32x4*)(wr + 0);
        f32x4 w1 = *(const f32x4*)(wr + 4);
        f32x4 w2 = *(const f32x4*)(wr + 8);
        f32x4 w3 = *(const f32x4*)(wr + 12);
        float td = v0.x*w0.x + v0.y*w0.y + v0.z*w0.z + v0.w*w0.w
                 + v1.x*w1.x + v1.y*w1.y + v1.z*w1.z + v1.w*w1.w
                 + v2.x*w2.x + v2.y*w2.y + v2.z*w2.z + v2.w*w2.w
                 + v3.x*w3.x + v3.y*w3.y + v3.z*w3.z + v3.w*w3.w;
        td += __shfl_xor(td, 1);
        td += __shfl_xor(td, 2);
        td += __shfl_xor(td, 4);
        td += __shfl_xor(td, 8);
        if (c == 0) tgt[row] = td * rinv;

        const float sc = rinv * S_LOG2E;
        const size_t fb = ((size_t)rg * 8 + (c >> 1)) * 512;   // frag (rg, kk=c>>1)
        const int kq0 = (c & 1) * 2;
        *(short8*)(Af + fb + (size_t)(kq0 * 16 + r) * 8)       = pack8(v0, v1, sc);
        *(short8*)(Af + fb + (size_t)((kq0 + 1) * 16 + r) * 8) = pack8(v2, v3, sc);
    } else {
        // plain row-major W -> bf16 (C*D exactly, no padding)
        int i = ((bid - PREPX_BLOCKS) * 256 + threadIdx.x) * 4;
        f32x4 v = *(const f32x4*)(W + i);
        short4v sv;
        sv.x = (short)__bfloat16_as_ushort(__float2bfloat16(v.x));
        sv.y = (short)__bfloat16_as_ushort(__float2bfloat16(v.y));
        sv.z = (short)__bfloat16_as_ushort(__float2bfloat16(v.z));
        sv.w = (short)__bfloat16_as_ushort(__float2bfloat16(v.w));
        *(short4v*)(Wb + i) = sv;
    }
}

// ---------------- main GEMM + exp2 + per-tile row partials ----------------
// R20 base (BN=80, 40 KB LDS, 4 blocks/CU capable, VGPR 84) + B LDS-read
// DOUBLE-BUFFER: step kk+1's 5 ds_read_b128 are issued BEFORE step kk's MFMA
// cluster, so each cluster's lgkmcnt wait covers reads issued a full cluster
// (~390 cyc) earlier — removes the per-step LDS latency from the critical
// path (R20's MfmaUtil plateau at 35% despite +50% occupancy localized the
// stall to this serial chain). +20 VGPR (b0/b1), target total ~104 <= 128.
__global__ __launch_bounds__(256) void gemm_exp(const bf16* __restrict__ Af,
                                                const bf16* __restrict__ Wb,
                                                bf16* __restrict__ partial) { // [NY][N] bf16
    __shared__ __align__(16) bf16 Bs[BN * D];   // 40 KB: [col][k], granule-swizzled

    // ---- XCD-aware decode (bijective: NWG = 8 * 8 * 125) ----
    const int bid = blockIdx.x;
    const int xcd = bid & 7;
    const int idx = bid >> 3;          // 0..999
    const int xl  = idx & 7;           // x within XCD chunk (fast)
    const int y   = idx >> 3;          // 0..124 (slow)
    const int tile_r = (xcd * 8 + xl) * BM;
    const int tile_c = y * BN;

    const int t = threadIdx.x;
    const int lane = t & 63, w = t >> 6;   // wave w owns rows w*64..+64, all 80 cols

    // ---- prologue: stage B panel (40 chunks of 1KB = 2 rows x 512B) ----
    #pragma unroll
    for (int q = 0; q < 10; ++q) {
        int c = w * 10 + q;                       // chunk 0..39, wave-uniform
        int row = 2 * c + (lane >> 5);            // B-panel row (= class col) 0..79
        int srcg = (lane & 31) ^ (row & 7);       // pre-swizzled source granule
        const bf16* gb = Wb + (size_t)(tile_c + row) * D + srcg * 8;
        __builtin_amdgcn_global_load_lds(
            (const __attribute__((address_space(1))) void*)gb,
            (__attribute__((address_space(3))) void*)(Bs + c * 512),
            16, 0, 0);
    }

    // ---- A fragment pointers (frag-order buffer, contiguous 1KB per frag) ----
    const bf16* ap[4];
    #pragma unroll
    for (int m = 0; m < 4; ++m)
        ap[m] = Af + ((size_t)((tile_r >> 4) + w * 4 + m) * 8) * 512 + lane * 8;

    f32x4 acc[4][5] = {};
    short8 a[2][4];
    #pragma unroll
    for (int m = 0; m < 4; ++m) a[0][m] = *(const short8*)(ap[m]);  // overlaps DMA

    DRAIN_DMA();
    __syncthreads();   // B panel fully visible; the ONLY K-path barrier

    const int g0 = lane >> 4;       // k-quad within fragment
    const int x7 = lane & 7;        // swizzle key (row&7 == lane&7 for frag rows)

    // B fragment read (kk = k-step, n = col-group); swizzled k-granule
    #define BREAD(kk, n) \
        (*(const short8*)(Bs + ((n) * 16 + (lane & 15)) * 256 + ((((kk) * 4 + g0) ^ x7)) * 8))

    short8 b0[5], b1[5];
    #pragma unroll
    for (int n = 0; n < 5; ++n) b0[n] = BREAD(0, n);   // cold start: step 0

    #pragma unroll
    for (int kk = 0; kk < 8; ++kk) {           // fully unrolled -> static indices
        const int cur = kk & 1, nxt = cur ^ 1;
        // issue NEXT step's loads first: A (global) and B (LDS)
        if (kk < 7) {
            #pragma unroll
            for (int m = 0; m < 4; ++m)
                a[nxt][m] = *(const short8*)(ap[m] + (kk + 1) * 512);
            if (cur == 0) {
                #pragma unroll
                for (int n = 0; n < 5; ++n) b1[n] = BREAD(kk + 1, n);
            } else {
                #pragma unroll
                for (int n = 0; n < 5; ++n) b0[n] = BREAD(kk + 1, n);
            }
        }
        // MFMA cluster on CURRENT buffers (reads issued one cluster ago)
        if (cur == 0) {
            #pragma unroll
            for (int m = 0; m < 4; ++m)
                #pragma unroll
                for (int n = 0; n < 5; ++n)
                    acc[m][n] = __builtin_amdgcn_mfma_f32_16x16x32_bf16(a[0][m], b0[n], acc[m][n], 0, 0, 0);
        } else {
            #pragma unroll
            for (int m = 0; m < 4; ++m)
                #pragma unroll
                for (int n = 0; n < 5; ++n)
                    acc[m][n] = __builtin_amdgcn_mfma_f32_16x16x32_bf16(a[1][m], b1[n], acc[m][n], 0, 0, 0);
        }
    }
    #undef BREAD

    __syncthreads();   // K-loop reads of Bs done; reuse as epilogue scratch
    float* eps = (float*)Bs;   // 256 floats

    // ---- epilogue: exp2(acc), row sums (rows unique per wave; all cols valid) ----
    #pragma unroll
    for (int m = 0; m < 4; ++m) {
        float rs[4] = {0.f, 0.f, 0.f, 0.f};
        #pragma unroll
        for (int n = 0; n < 5; ++n) {
            #pragma unroll
            for (int r = 0; r < 4; ++r)
                rs[r] += __builtin_amdgcn_exp2f(acc[m][n][r]);
        }
        #pragma unroll
        for (int r = 0; r < 4; ++r) {
            float v = rs[r];
            v += __shfl_xor(v, 1);
            v += __shfl_xor(v, 2);
            v += __shfl_xor(v, 4);
            v += __shfl_xor(v, 8);
            if ((lane & 15) == 0)
                eps[w * 64 + m * 16 + (lane >> 4) * 4 + r] = v;
        }
    }
    __syncthreads();
    partial[(size_t)y * N + tile_r + t] = __float2bfloat16(eps[t]);  // coalesced
}

// ---------------- loss: reduce partials (5-way ILP) + per-row loss + atomic ----------------
__global__ __launch_bounds__(256) void loss_part(const float* __restrict__ tgt,
                                                 const bf16* __restrict__ partial,
                                                 float* __restrict__ out) {
    int i = blockIdx.x * 256 + threadIdx.x;   // row
    // 5 independent accumulator chains (NY = 125 = 5 * 25) for load ILP
    float s0 = 0.f, s1 = 0.f, s2 = 0.f, s3 = 0.f, s4 = 0.f;
    #pragma unroll 1
    for (int y = 0; y < NY; y += 5) {
        s0 += __bfloat162float(partial[(size_t)(y + 0) * N + i]);
        s1 += __bfloat162float(partial[(size_t)(y + 1) * N + i]);
        s2 += __bfloat162float(partial[(size_t)(y + 2) * N + i]);
        s3 += __bfloat162float(partial[(size_t)(y + 3) * N + i]);
        s4 += __bfloat162float(partial[(size_t)(y + 4) * N + i]);
    }
    float sum = ((s0 + s1) + (s2 + s3)) + s4;

    float tg = tgt[i];
    float num = S * (tg - MARGIN);
    float den = __expf(num) + sum - __expf(S * tg);
    float L = num - logf(den);

    float v = L;
    #pragma unroll
    for (int off = 1; off < 64; off <<= 1) v += __shfl_xor(v, off);
    __shared__ float s4m[4];
    int lane = threadIdx.x & 63, w = threadIdx.x >> 6;
    if (lane == 0) s4m[w] = v;
    __syncthreads();
    if (threadIdx.x == 0) {
        float bsum = s4m[0] + s4m[1] + s4m[2] + s4m[3];
        atomicAdd(out, -bsum / (float)N);
    }
}

// ---------------- launch ----------------
extern "C" void kernel_launch(void* const* d_in, const int* in_sizes, int n_in,
                              void* d_out, int out_size, void* d_ws, size_t ws_size,
                              hipStream_t stream) {
    const float* x = (const float*)d_in[0];
    const int* labels = (const int*)d_in[1];
    const float* W = (const float*)d_in[2];

    char* ws = (char*)d_ws;
    bf16* Af       = (bf16*)(ws);                    // N*D*2 (frag order)   =  8,388,608
    bf16* Wb       = (bf16*)(ws + 8388608);          // C*D*2 (row-major)    =  5,120,000
    float* tgt     = (float*)(ws + 13508608);        // N*4                  =     65,536
    bf16* partial  = (bf16*)(ws + 13574144);         // NY*N*2               =  4,096,000
    float* out = (float*)d_out;                      // total 17,670,144

    prep<<<PREPX_BLOCKS + PREPW_BLOCKS, 256, 0, stream>>>(x, labels, W, Af, tgt, Wb, out);
    gemm_exp<<<NWG, 256, 0, stream>>>(Af, Wb, partial);
    loss_part<<<N / 256, 256, 0, stream>>>(tgt, partial, out);
}

// Round 22
// 92.188 us; speedup vs baseline: 1.5040x; 1.2615x over previous
//
#include <hip/hip_runtime.h>
#include <hip/hip_bf16.h>
#include <math.h>

constexpr int N = 16384, D = 256, C = 10000;
constexpr float S = 30.0f, MARGIN = 0.4f;
constexpr int BM = 128, BN = 80;             // C == 125*80 exactly: no padding
constexpr int NX = N / BM;                   // 128 row tiles
constexpr int NY = C / BN;                   // 125 col tiles
constexpr int NWG = NX * NY;                 // 16000 = 8 * 16 * 125
constexpr float S_LOG2E = 43.2808512266689f; // S * log2(e)  (applied in epilogue)

constexpr int PREPX_BLOCKS = N / 16;          // 1024 (16-row groups, fp8 frag pack)
constexpr int PREPW_BLOCKS = C / 16;          // 625  (16-col groups, fp8 frag pack)

using bf16 = __hip_bfloat16;
typedef __attribute__((ext_vector_type(4))) int   int4v;
typedef __attribute__((ext_vector_type(8))) int   int8v;
typedef __attribute__((ext_vector_type(4))) float f32x4;

#define DRAIN_DMA()                                        \
    do {                                                   \
        asm volatile("s_waitcnt vmcnt(0)" ::: "memory");   \
        __builtin_amdgcn_sched_barrier(0);                 \
    } while (0)

// pack 4 floats -> 4 fp8(e4m3) bytes in one dword (little-endian order e0..e3)
__device__ inline int pk4_fp8(float e0, float e1, float e2, float e3) {
    int lo = __builtin_amdgcn_cvt_pk_fp8_f32(e0, e1, 0, false);   // bytes 0,1
    return  __builtin_amdgcn_cvt_pk_fp8_f32(e2, e3, lo, true);    // bytes 2,3
}

// ---------------- fused prep ----------------
// Both operands packed into the K=128 fp8 fragment layout:
//   frag (g16, kk) = 2048 B; lane l covers row g16*16+(l&15),
//   k = kk*128 + (l>>4)*32 + j, j=0..31; byte addr within frag =
//   (j>>4)*1024 + l*16 + (j&15)   [two 16B halves per lane -> conflict-free
//   ds_read_b128 and dwordx4 pattern]. A and B use the IDENTICAL bijection,
//   so any within-lane k-order yields the exact dot product; uniform scale
//   0x7F (=1.0) makes scale-block indexing immaterial.
// x: normalize (f32), convert xn (unscaled, |el|~0.06) to e4m3. tgt in f32.
// W: convert to e4m3 (no padding: C = 625*16).
__global__ __launch_bounds__(256) void prep(const float* __restrict__ x,
                                            const int* __restrict__ labels,
                                            const float* __restrict__ W,
                                            char* __restrict__ Af,
                                            float* __restrict__ tgt,
                                            char* __restrict__ Bf,
                                            float* __restrict__ out) {
    const int bid = blockIdx.x;
    if (bid == 0 && threadIdx.x == 0) out[0] = 0.0f;

    const int tl = threadIdx.x;
    const int r = tl >> 4, c = tl & 15;
    // fragment byte address for this thread's 16 elements (d = c*16 .. +16):
    //   kk = c>>3, half = c&1, q = (c>>1)&3, lane = q*16+r
    auto frag_off = [&](int g16) -> size_t {
        return ((size_t)g16 * 2 + (c >> 3)) * 2048 + (size_t)(c & 1) * 1024
             + (size_t)((((c >> 1) & 3) * 16 + r)) * 16;
    };

    if (bid < PREPX_BLOCKS) {
        const int rg = bid;
        const int row = rg * 16 + r;
        const float* xr = x + (size_t)row * D + c * 16;
        f32x4 v0 = *(const f32x4*)(xr + 0);
        f32x4 v1 = *(const f32x4*)(xr + 4);
        f32x4 v2 = *(const f32x4*)(xr + 8);
        f32x4 v3 = *(const f32x4*)(xr + 12);

        float ssq = v0.x*v0.x + v0.y*v0.y + v0.z*v0.z + v0.w*v0.w
                  + v1.x*v1.x + v1.y*v1.y + v1.z*v1.z + v1.w*v1.w
                  + v2.x*v2.x + v2.y*v2.y + v2.z*v2.z + v2.w*v2.w
                  + v3.x*v3.x + v3.y*v3.y + v3.z*v3.z + v3.w*v3.w;
        ssq += __shfl_xor(ssq, 1);
        ssq += __shfl_xor(ssq, 2);
        ssq += __shfl_xor(ssq, 4);
        ssq += __shfl_xor(ssq, 8);
        float rinv = rsqrtf(ssq);

        const int lab = labels[row];
        const float* wr = W + (size_t)lab * D + c * 16;
        f32x4 w0 = *(const f32x4*)(wr + 0);
        f32x4 w1 = *(const f32x4*)(wr + 4);
        f32x4 w2 = *(const f32x4*)(wr + 8);
        f32x4 w3 = *(const f32x4*)(wr + 12);
        float td = v0.x*w0.x + v0.y*w0.y + v0.z*w0.z + v0.w*w0.w
                 + v1.x*w1.x + v1.y*w1.y + v1.z*w1.z + v1.w*w1.w
                 + v2.x*w2.x + v2.y*w2.y + v2.z*w2.z + v2.w*w2.w
                 + v3.x*w3.x + v3.y*w3.y + v3.z*w3.z + v3.w*w3.w;
        td += __shfl_xor(td, 1);
        td += __shfl_xor(td, 2);
        td += __shfl_xor(td, 4);
        td += __shfl_xor(td, 8);
        if (c == 0) tgt[row] = td * rinv;   // exact f32 numerator path

        int4v pk;
        pk.x = pk4_fp8(v0.x * rinv, v0.y * rinv, v0.z * rinv, v0.w * rinv);
        pk.y = pk4_fp8(v1.x * rinv, v1.y * rinv, v1.z * rinv, v1.w * rinv);
        pk.z = pk4_fp8(v2.x * rinv, v2.y * rinv, v2.z * rinv, v2.w * rinv);
        pk.w = pk4_fp8(v3.x * rinv, v3.y * rinv, v3.z * rinv, v3.w * rinv);
        *(int4v*)(Af + frag_off(rg)) = pk;
    } else {
        const int rg = bid - PREPX_BLOCKS;     // 16-col group 0..624
        const int row = rg * 16 + r;           // class index (< C always)
        const float* wr = W + (size_t)row * D + c * 16;
        f32x4 v0 = *(const f32x4*)(wr + 0);
        f32x4 v1 = *(const f32x4*)(wr + 4);
        f32x4 v2 = *(const f32x4*)(wr + 8);
        f32x4 v3 = *(const f32x4*)(wr + 12);
        int4v pk;
        pk.x = pk4_fp8(v0.x, v0.y, v0.z, v0.w);
        pk.y = pk4_fp8(v1.x, v1.y, v1.z, v1.w);
        pk.z = pk4_fp8(v2.x, v2.y, v2.z, v2.w);
        pk.w = pk4_fp8(v3.x, v3.y, v3.z, v3.w);
        *(int4v*)(Bf + frag_off(rg)) = pk;
    }
}

// ---------------- main GEMM (MX-fp8 K=128) + exp2 + per-tile row partials ----------------
// BM=128 x BN=80, 4 waves, per-wave 32x80 (acc[2][5] = 40 VGPR). B panel
// (5 col-groups x 2 k-blocks = 10 frags, 20 KB) staged linearly into LDS;
// A fragments (2x2 = 128 B/lane) loaded fully into registers before the
// single barrier. K-"loop" = 2 scaled-MFMA steps, all operands resident or
// one LDS-read away. Uniform scale 0x7F7F7F7F (=1.0 in every byte).
__global__ __launch_bounds__(256) void gemm_exp(const char* __restrict__ Af,
                                                const char* __restrict__ Bf,
                                                bf16* __restrict__ partial) { // [NY][N] bf16
    __shared__ __align__(16) char Bs[BN * D];   // 20 KB, fragment order

    // ---- XCD-aware decode (bijective: NWG = 8 * 16 * 125) ----
    const int bid = blockIdx.x;
    const int xcd = bid & 7;
    const int idx = bid >> 3;          // 0..1999
    const int xl  = idx & 15;          // x within XCD chunk (fast)
    const int y   = idx >> 4;          // 0..124 (slow)
    const int tile_r = (xcd * 16 + xl) * BM;
    const int tile_c = y * BN;

    const int t = threadIdx.x;
    const int lane = t & 63, w = t >> 6;   // wave w owns rows w*32..+32, all 80 cols

    // ---- prologue: stage B panel = linear 20 KB copy (frag order preserved) ----
    #pragma unroll
    for (int q = 0; q < 5; ++q) {
        int cch = w * 5 + q;                      // chunk 0..19, wave-uniform
        const char* gb = Bf + (size_t)y * 10 * 2048 + (size_t)cch * 1024 + lane * 16;
        __builtin_amdgcn_global_load_lds(
            (const __attribute__((address_space(1))) void*)gb,
            (__attribute__((address_space(3))) void*)(Bs + cch * 1024),
            16, 0, 0);
    }

    // ---- A fragments: fully register-resident (2 m x 2 kk x 32 B/lane) ----
    int8v a[2][2];   // [kk][m]
    #pragma unroll
    for (int kk = 0; kk < 2; ++kk)
        #pragma unroll
        for (int m = 0; m < 2; ++m) {
            const char* base = Af + ((size_t)((tile_r >> 4) + w * 2 + m) * 2 + kk) * 2048;
            int4v lo = *(const int4v*)(base + lane * 16);
            int4v hi = *(const int4v*)(base + 1024 + lane * 16);
            a[kk][m] = int8v{lo.x, lo.y, lo.z, lo.w, hi.x, hi.y, hi.z, hi.w};
        }

    f32x4 acc[2][5] = {};

    DRAIN_DMA();
    __syncthreads();   // B panel fully visible; the ONLY K-path barrier

    #pragma unroll
    for (int kk = 0; kk < 2; ++kk) {
        int8v b[5];
        #pragma unroll
        for (int n = 0; n < 5; ++n) {
            const char* base = Bs + (n * 2 + kk) * 2048;
            int4v lo = *(const int4v*)(base + lane * 16);
            int4v hi = *(const int4v*)(base + 1024 + lane * 16);
            b[n] = int8v{lo.x, lo.y, lo.z, lo.w, hi.x, hi.y, hi.z, hi.w};
        }
        #pragma unroll
        for (int m = 0; m < 2; ++m)
            #pragma unroll
            for (int n = 0; n < 5; ++n)
                acc[m][n] = __builtin_amdgcn_mfma_scale_f32_16x16x128_f8f6f4(
                    a[kk][m], b[n], acc[m][n],
                    0 /*cbsz: fp8*/, 0 /*blgp: fp8*/,
                    0, 0x7F7F7F7F,   // scale A = 1.0 (every byte)
                    0, 0x7F7F7F7F);  // scale B = 1.0
    }

    __syncthreads();   // K-loop reads of Bs done; reuse as epilogue scratch
    float* eps = (float*)Bs;   // 128 floats

    // ---- epilogue: exp2(S_LOG2E * acc), row sums (rows unique per wave) ----
    #pragma unroll
    for (int m = 0; m < 2; ++m) {
        float rs[4] = {0.f, 0.f, 0.f, 0.f};
        #pragma unroll
        for (int n = 0; n < 5; ++n) {
            #pragma unroll
            for (int r = 0; r < 4; ++r)
                rs[r] += __builtin_amdgcn_exp2f(acc[m][n][r] * S_LOG2E);
        }
        #pragma unroll
        for (int r = 0; r < 4; ++r) {
            float v = rs[r];
            v += __shfl_xor(v, 1);
            v += __shfl_xor(v, 2);
            v += __shfl_xor(v, 4);
            v += __shfl_xor(v, 8);
            if ((lane & 15) == 0)
                eps[w * 32 + m * 16 + (lane >> 4) * 4 + r] = v;
        }
    }
    __syncthreads();
    if (t < BM)
        partial[(size_t)y * N + tile_r + t] = __float2bfloat16(eps[t]);  // coalesced
}

// ---------------- loss: reduce partials (5-way ILP) + per-row loss + atomic ----------------
__global__ __launch_bounds__(256) void loss_part(const float* __restrict__ tgt,
                                                 const bf16* __restrict__ partial,
                                                 float* __restrict__ out) {
    int i = blockIdx.x * 256 + threadIdx.x;   // row
    float s0 = 0.f, s1 = 0.f, s2 = 0.f, s3 = 0.f, s4 = 0.f;
    #pragma unroll 1
    for (int y = 0; y < NY; y += 5) {
        s0 += __bfloat162float(partial[(size_t)(y + 0) * N + i]);
        s1 += __bfloat162float(partial[(size_t)(y + 1) * N + i]);
        s2 += __bfloat162float(partial[(size_t)(y + 2) * N + i]);
        s3 += __bfloat162float(partial[(size_t)(y + 3) * N + i]);
        s4 += __bfloat162float(partial[(size_t)(y + 4) * N + i]);
    }
    float sum = ((s0 + s1) + (s2 + s3)) + s4;

    float tg = tgt[i];
    float num = S * (tg - MARGIN);
    float den = __expf(num) + sum - __expf(S * tg);
    float L = num - logf(den);

    float v = L;
    #pragma unroll
    for (int off = 1; off < 64; off <<= 1) v += __shfl_xor(v, off);
    __shared__ float s4m[4];
    int lane = threadIdx.x & 63, w = threadIdx.x >> 6;
    if (lane == 0) s4m[w] = v;
    __syncthreads();
    if (threadIdx.x == 0) {
        float bsum = s4m[0] + s4m[1] + s4m[2] + s4m[3];
        atomicAdd(out, -bsum / (float)N);
    }
}

// ---------------- launch ----------------
extern "C" void kernel_launch(void* const* d_in, const int* in_sizes, int n_in,
                              void* d_out, int out_size, void* d_ws, size_t ws_size,
                              hipStream_t stream) {
    const float* x = (const float*)d_in[0];
    const int* labels = (const int*)d_in[1];
    const float* W = (const float*)d_in[2];

    char* ws = (char*)d_ws;
    char* Af       = ws;                             // N*D fp8 (frag order)  = 4,194,304
    char* Bf       = ws + 4194304;                   // C*D fp8 (frag order)  = 2,560,000
    float* tgt     = (float*)(ws + 6754304);         // N*4                   =    65,536
    bf16* partial  = (bf16*)(ws + 6819840);          // NY*N*2                = 4,096,000
    float* out = (float*)d_out;                      // total 10,915,840

    prep<<<PREPX_BLOCKS + PREPW_BLOCKS, 256, 0, stream>>>(x, labels, W, Af, tgt, Bf, out);
    gemm_exp<<<NWG, 256, 0, stream>>>(Af, Bf, partial);
    loss_part<<<N / 256, 256, 0, stream>>>(tgt, partial, out);
}